// Round 4
// baseline (12076.034 us; speedup 1.0000x reference)
//
#include <hip/hip_runtime.h>
#include <hip/hip_fp16.h>
#include <math.h>

// Problem constants
#define NB 64
#define NS 128
#define ND 128
#define NV 512
#define NC 256
#define NN 256
#define NM 64
#define NG 1024
#define KIH 192
#define KZ  320
#define HST 208
#define MPAD 65

// ws layout: fp16 weights packed as uint2 (4 halves each), then fp32 biases, then hrv
#define U2_WIH 0          // [KIH][NG] -> 192*256 uint2
#define U2_WHH 49152      // [NC][NG]  -> 256*256
#define U2_HWT 114688     // [NC][208] -> 256*52
#define U2_OUT 128000     // [KZ][NV]  -> 320*128
#define U2_END 168960
#define F_BSUM 337920     // 1024 floats (= U2_END*2)
#define F_HB   338944     // 208 floats (pad to 256)
#define F_HRV  339200     // 8192*320 floats
#define WS_SPLIT_BYTES 11842560u
#define PREP_ITEMS (U2_END + NG + HST)

// LDS layout (floats)
#define L_MEM 0
#define L_H   (NN*MPAD)          // 16640
#define L_C   (L_H + NC)
#define L_RW  (L_C + NC)
#define L_W   (L_RW + NN)
#define L_RV  (L_W + NN)
#define L_CI  (L_RV + NM)        // 16B-aligned (17728*4)
#define L_HD  (L_CI + KIH)
#define L_SIM (L_HD + HST)
#define L_PART (L_SIM + NN)      // 16B aligned
#define SMEM_FLOATS (L_PART + 4096)
#define SMEM_BYTES (SMEM_FLOATS * 4)   // 89920 B

__device__ __forceinline__ float sigf(float x) { return 1.0f / (1.0f + expf(-x)); }
__device__ __forceinline__ float splus(float x) { return (x > 20.f) ? x : log1pf(expf(x)); }

// fp16 unpack: low/high half of a uint
__device__ __forceinline__ float hlo(unsigned u) {
  unsigned short s = (unsigned short)(u & 0xffffu);
  _Float16 h;
  __builtin_memcpy(&h, &s, 2);
  return (float)h;
}
__device__ __forceinline__ float hhi(unsigned u) {
  unsigned short s = (unsigned short)(u >> 16);
  _Float16 h;
  __builtin_memcpy(&h, &s, 2);
  return (float)h;
}
__device__ __forceinline__ unsigned short f2h(float f) {  // RNE
  _Float16 h = (_Float16)f;
  unsigned short s;
  __builtin_memcpy(&s, &h, 2);
  return s;
}

__device__ float head_w(int c, int k, const float* kW, const float* eW, const float* aW,
                        const float* sW, const float* bW, const float* gW, const float* gaW) {
  if (c < 64)  return kW[c * NC + k];
  if (c < 128) return eW[(c - 64) * NC + k];
  if (c < 192) return aW[(c - 128) * NC + k];
  if (c < 195) return sW[(c - 192) * NC + k];
  if (c == 195) return bW[k];
  if (c == 196) return gW[k];
  if (c == 197) return gaW[k];
  return 0.0f;
}

// ---------------- Preprocess: transpose + fp16-pack weights into ws ----------------
__global__ void ntm_prep(const float* __restrict__ W_ih, const float* __restrict__ W_hh,
                         const float* __restrict__ b_ih, const float* __restrict__ b_hh,
                         const float* __restrict__ key_W, const float* __restrict__ key_b,
                         const float* __restrict__ beta_W, const float* __restrict__ beta_b,
                         const float* __restrict__ gate_W, const float* __restrict__ gate_b,
                         const float* __restrict__ shift_W, const float* __restrict__ shift_b,
                         const float* __restrict__ gamma_W, const float* __restrict__ gamma_b,
                         const float* __restrict__ erase_W, const float* __restrict__ erase_b,
                         const float* __restrict__ add_W, const float* __restrict__ add_b,
                         const float* __restrict__ out_W, float* __restrict__ ws)
{
  uint2* w4 = (uint2*)ws;
  for (int idx = blockIdx.x * blockDim.x + threadIdx.x; idx < PREP_ITEMS;
       idx += gridDim.x * blockDim.x) {
    if (idx < U2_END) {
      float v[4];
      if (idx < U2_WHH) {
        int k = idx >> 8, og = idx & 255;
        #pragma unroll
        for (int j = 0; j < 4; ++j) v[j] = W_ih[(og * 4 + j) * KIH + k];
      } else if (idx < U2_HWT) {
        int i = idx - U2_WHH, k = i >> 8, og = i & 255;
        #pragma unroll
        for (int j = 0; j < 4; ++j) v[j] = W_hh[(og * 4 + j) * NC + k];
      } else if (idx < U2_OUT) {
        int i = idx - U2_HWT, k = i / 52, cq = i % 52;
        #pragma unroll
        for (int j = 0; j < 4; ++j)
          v[j] = head_w(cq * 4 + j, k, key_W, erase_W, add_W, shift_W, beta_W, gate_W, gamma_W);
      } else {
        int i = idx - U2_OUT, k = i >> 7, og = i & 127;
        #pragma unroll
        for (int j = 0; j < 4; ++j) v[j] = out_W[(og * 4 + j) * KZ + k];
      }
      uint2 p;
      p.x = (unsigned)f2h(v[0]) | ((unsigned)f2h(v[1]) << 16);
      p.y = (unsigned)f2h(v[2]) | ((unsigned)f2h(v[3]) << 16);
      w4[idx] = p;
    } else if (idx < U2_END + NG) {
      int o = idx - U2_END;
      ws[F_BSUM + o] = b_ih[o] + b_hh[o];
    } else {
      int c = idx - U2_END - NG;
      float v;
      if (c < 64)       v = key_b[c];
      else if (c < 128) v = erase_b[c - 64];
      else if (c < 192) v = add_b[c - 128];
      else if (c < 195) v = shift_b[c - 192];
      else if (c == 195) v = beta_b[0];
      else if (c == 196) v = gate_b[0];
      else               v = gamma_b[0];   // c == 197
      ws[F_HB + c] = v;
    }
  }
}

// ---------------- Main: one block per batch element, weights pinned in VGPRs ----------------
template <int SPLIT>
__launch_bounds__(1024, 1)
__global__ void ntm_main(const int* __restrict__ x, const float* __restrict__ emb,
                         const float* __restrict__ out_b, const float* __restrict__ mem_init,
                         const float* __restrict__ ws, float* __restrict__ out)
{
  const int b = blockIdx.x;
  const int tid = threadIdx.x;
  const uint2* WIH4 = (const uint2*)ws;
  const uint2* WHH4 = WIH4 + U2_WHH;
  const uint2* HWT4 = WIH4 + U2_HWT;
  const uint2* OUT4 = WIH4 + U2_OUT;
  const float* bsum = ws + F_BSUM;
  const float* hb   = ws + F_HB;
  float* hrv = (float*)(ws + F_HRV);

  extern __shared__ float sm[];
  float* s_mem = sm + L_MEM;
  float* s_h   = sm + L_H;
  float* s_c   = sm + L_C;
  float* s_rw  = sm + L_RW;
  float* s_w   = sm + L_W;
  float* s_rv  = sm + L_RV;
  float* s_ci  = sm + L_CI;
  float* s_hd  = sm + L_HD;
  float* s_sim = sm + L_SIM;
  float* s_part = sm + L_PART;
  float4* s_part4 = (float4*)s_part;

  // per-thread constant mappings
  const int og2 = tid & 255, q2 = tid >> 8;          // phase 2 (4 outs x 112 k in regs)
  const int c4 = tid % 208, q4 = tid / 208;          // phase 4 (tid<832): 1 col x 64 k
  const int n6 = tid >> 2, q6 = tid & 3;             // phase 6
  const int m8 = tid & 63, q8 = tid >> 6;            // phase 8

  // ---- preload ALL recurrent weights into registers (one-time) ----
  uint2 wih[48];   // 96 VGPR: WIH[k=q2*48 .. +47][og2*4 .. +3]
  {
    const uint2* p = WIH4 + (q2 * 48) * 256 + og2;
    #pragma unroll
    for (int kk = 0; kk < 48; ++kk) wih[kk] = p[kk * 256];
  }
  uint2 whh[64];   // 128 VGPR: WHH[k=q2*64 .. +63][og2*4 .. +3]
  {
    const uint2* p = WHH4 + (q2 * 64) * 256 + og2;
    #pragma unroll
    for (int kk = 0; kk < 64; ++kk) whh[kk] = p[kk * 256];
  }
  unsigned hwt[32];  // 32 VGPR: HWT[k=q4*64 .. +63][c4] (2 halves/reg), tid<832
  if (tid < 832) {
    int cq = c4 >> 2, sub = c4 & 3;
    #pragma unroll
    for (int j = 0; j < 32; ++j) {
      int k0 = q4 * 64 + 2 * j;
      uint2 v0 = HWT4[k0 * 52 + cq];
      uint2 v1 = HWT4[(k0 + 1) * 52 + cq];
      unsigned h0 = (((sub & 2) ? v0.y : v0.x) >> ((sub & 1) * 16)) & 0xffffu;
      unsigned h1 = (((sub & 2) ? v1.y : v1.x) >> ((sub & 1) * 16)) & 0xffffu;
      hwt[j] = h0 | (h1 << 16);
    }
  }
  // scalar bias preloads
  float bs0 = 0.f, bs1 = 0.f, bs2 = 0.f, bs3 = 0.f, hbv = 0.f;
  if (tid < NC) {
    bs0 = bsum[tid]; bs1 = bsum[NC + tid]; bs2 = bsum[2 * NC + tid]; bs3 = bsum[3 * NC + tid];
    hbv = hb[tid];   // only tid<HST meaningful
  }

  // init state
  for (int i = tid; i < NN * NM; i += 1024) {
    int n = i >> 6, m = i & 63;
    s_mem[n * MPAD + m] = mem_init[b * NN * NM + i];
  }
  if (tid < NC) { s_h[tid] = 0.f; s_c[tid] = 0.f; }
  if (tid < NN) s_rw[tid] = 0.f;
  if (tid < NM) s_rv[tid] = 0.f;

  // embedding prefetch for t=0
  float e_reg = 0.f;
  if (tid < ND) e_reg = emb[x[b * NS] * ND + tid];
  __syncthreads();

  for (int t = 0; t < NS; ++t) {
    // ---- phase A: ci = [emb, rv]; store hrv of step t-1 (SPLIT); prefetch emb t+1 ----
    {
      if (tid < KIH) s_ci[tid] = (tid < ND) ? e_reg : s_rv[tid - ND];
      if (SPLIT && t > 0 && tid >= 192 && tid < 512) {
        int i = tid - 192;
        hrv[(size_t)(b * NS + (t - 1)) * KZ + i] = (i < NC) ? s_h[i] : s_rv[i - NC];
      }
    }
    if (t + 1 < NS && tid < ND) e_reg = emb[x[b * NS + t + 1] * ND + tid];
    __syncthreads();  // S1

    // ---- phase 2: gate partials from registers (4 outs x 112 k) ----
    {
      float4 acc = {0.f, 0.f, 0.f, 0.f};
      const float* cip = s_ci + q2 * 48;
      #pragma unroll
      for (int kk = 0; kk < 48; ++kk) {
        uint2 w = wih[kk];
        float a = cip[kk];
        acc.x = fmaf(hlo(w.x), a, acc.x); acc.y = fmaf(hhi(w.x), a, acc.y);
        acc.z = fmaf(hlo(w.y), a, acc.z); acc.w = fmaf(hhi(w.y), a, acc.w);
      }
      const float* hp = s_h + q2 * 64;
      #pragma unroll
      for (int kk = 0; kk < 64; ++kk) {
        uint2 w = whh[kk];
        float a = hp[kk];
        acc.x = fmaf(hlo(w.x), a, acc.x); acc.y = fmaf(hhi(w.x), a, acc.y);
        acc.z = fmaf(hlo(w.y), a, acc.z); acc.w = fmaf(hhi(w.y), a, acc.w);
      }
      s_part4[q2 * 256 + og2] = acc;
    }
    __syncthreads();  // S2

    // ---- phase 3: combine gates + LSTM cell (torch order i,f,g,o) ----
    if (tid < NC) {
      float gi = bs0, gf = bs1, gg = bs2, go = bs3;
      #pragma unroll
      for (int q = 0; q < 4; ++q) {
        const float* pp = s_part + q * NG;
        gi += pp[tid]; gf += pp[NC + tid]; gg += pp[2 * NC + tid]; go += pp[3 * NC + tid];
      }
      float cn = sigf(gf) * s_c[tid] + sigf(gi) * tanhf(gg);
      s_c[tid] = cn;
      s_h[tid] = sigf(go) * tanhf(cn);
    }
    __syncthreads();  // S3

    // ---- phase 4: head-linear partials from registers (208 cols x 4 k-chunks) ----
    if (tid < 832) {
      float acc = 0.f;
      const float* hp = s_h + q4 * 64;
      #pragma unroll
      for (int j = 0; j < 32; ++j) {
        unsigned u = hwt[j];
        acc = fmaf(hlo(u), hp[2 * j], acc);
        acc = fmaf(hhi(u), hp[2 * j + 1], acc);
      }
      s_part[q4 * HST + c4] = acc;
    }
    __syncthreads();  // S4

    // ---- phase 5: combine + activations (wave-aligned) ----
    if (tid < 256) {
      float val = 0.f;
      if (tid < HST) {
        val = hbv;
        #pragma unroll
        for (int q = 0; q < 4; ++q) val += s_part[q * HST + tid];
      }
      int wv = tid >> 6;
      if (wv == 0) {            // key l2-normalize
        float ss = val * val;
        for (int off = 32; off; off >>= 1) ss += __shfl_xor(ss, off);
        s_hd[tid] = val / fmaxf(sqrtf(ss), 1e-12f);
      } else if (wv == 1) {     // erase: sigmoid
        s_hd[tid] = sigf(val);
      } else if (wv == 2) {     // add: tanh
        s_hd[tid] = tanhf(val);
      } else {                  // wave 3: shift softmax + scalars
        int l = tid & 63;
        float a0 = __shfl(val, 0), a1 = __shfl(val, 1), a2 = __shfl(val, 2);
        float mx = fmaxf(a0, fmaxf(a1, a2));
        float e0 = expf(a0 - mx), e1 = expf(a1 - mx), e2 = expf(a2 - mx);
        float ss = e0 + e1 + e2;
        float r = 0.f;
        if (l == 0) r = e0 / ss;
        else if (l == 1) r = e1 / ss;
        else if (l == 2) r = e2 / ss;
        else if (l == 3) r = splus(val);          // beta  (col 195)
        else if (l == 4) r = sigf(val);           // gate  (col 196)
        else if (l == 5) r = 1.0f + splus(val);   // gamma (col 197)
        if (l < 16) s_hd[192 + l] = r;
      }
    }
    __syncthreads();  // S5

    // ---- phase 6: cosine sim (4 lanes per memory row) ----
    {
      const float* mrow = s_mem + n6 * MPAD + q6 * 16;
      const float* kp = s_hd + q6 * 16;
      float dot = 0.f, sq = 0.f;
      #pragma unroll
      for (int i = 0; i < 16; ++i) {
        float mv = mrow[i];
        dot = fmaf(mv, kp[i], dot);
        sq  = fmaf(mv, mv, sq);
      }
      dot += __shfl_xor(dot, 1); dot += __shfl_xor(dot, 2);
      sq  += __shfl_xor(sq, 1);  sq  += __shfl_xor(sq, 2);
      if (q6 == 0) s_sim[n6] = dot / fmaxf(sqrtf(sq), 1e-12f);
    }
    __syncthreads();  // S6

    // ---- phase 7: full addressing chain in one wave (4 slots/lane) ----
    if (tid < 64) {
      int l = tid;
      float beta = s_hd[195], gate = s_hd[196], gamma = s_hd[197];
      float sh0 = s_hd[192], sh1 = s_hd[193], sh2 = s_hd[194];
      float v0 = beta * s_sim[l], v1 = beta * s_sim[64 + l];
      float v2 = beta * s_sim[128 + l], v3 = beta * s_sim[192 + l];
      float mx = fmaxf(fmaxf(v0, v1), fmaxf(v2, v3));
      for (int off = 32; off; off >>= 1) mx = fmaxf(mx, __shfl_xor(mx, off));
      float e0 = expf(v0 - mx), e1 = expf(v1 - mx), e2 = expf(v2 - mx), e3 = expf(v3 - mx);
      float s = e0 + e1 + e2 + e3;
      for (int off = 32; off; off >>= 1) s += __shfl_xor(s, off);
      float inv = 1.0f / s, omg = 1.0f - gate;
      float wg[4];
      wg[0] = gate * e0 * inv + omg * s_rw[l];
      wg[1] = gate * e1 * inv + omg * s_rw[64 + l];
      wg[2] = gate * e2 * inv + omg * s_rw[128 + l];
      wg[3] = gate * e3 * inv + omg * s_rw[192 + l];
      float p[4]; float ps = 0.f;
      #pragma unroll
      for (int j = 0; j < 4; ++j) {
        float cu = (l == 0) ? wg[(j + 1) & 3] : wg[j];
        float up = __shfl(cu, (l + 1) & 63);
        float cd = (l == 63) ? wg[(j + 3) & 3] : wg[j];
        float dn = __shfl(cd, (l + 63) & 63);
        float wn = fmaf(sh0, up, fmaf(sh1, wg[j], sh2 * dn));
        p[j] = powf(wn, gamma);
        ps += p[j];
      }
      for (int off = 32; off; off >>= 1) ps += __shfl_xor(ps, off);
      float invp = 1.0f / ps;
      #pragma unroll
      for (int j = 0; j < 4; ++j) {
        float wv = p[j] * invp;
        s_w[l + 64 * j] = wv;
        s_rw[l + 64 * j] = wv;
      }
    }
    __syncthreads();  // S7

    // ---- phase 8: rv partials = w @ mem (16 n-chunks x 64 m) ----
    {
      float acc = 0.f;
      int n0 = q8 * 16;
      #pragma unroll
      for (int i = 0; i < 16; ++i) {
        int n = n0 + i;
        acc = fmaf(s_w[n], s_mem[n * MPAD + m8], acc);
      }
      s_part[q8 * 64 + m8] = acc;
    }
    __syncthreads();  // S8

    // ---- phase 9: rv combine + memory update ----
    if (tid < NM) {
      float acc = 0.f;
      #pragma unroll
      for (int q = 0; q < 16; ++q) acc += s_part[q * 64 + tid];
      s_rv[tid] = acc;
    }
    for (int i = tid; i < NN * NM; i += 1024) {
      int n = i >> 6, m = i & 63;
      float wv = s_w[n];
      float cur = s_mem[n * MPAD + m];
      s_mem[n * MPAD + m] = cur * (1.f - wv * s_hd[64 + m]) + wv * s_hd[128 + m];
    }
    __syncthreads();  // S9

    if (!SPLIT) {
      // fused logits fallback: 4 cols x 8 k-chunks of 40 per thread (streams OUT4)
      {
        int ogo = tid & 127, qo = tid >> 7;
        const uint2* pw = OUT4 + (qo * 40) * 128 + ogo;
        float4 acc = {0.f, 0.f, 0.f, 0.f};
        #pragma unroll 8
        for (int kk = 0; kk < 40; ++kk) {
          int k = qo * 40 + kk;
          float a = (k < NC) ? s_h[k] : s_rv[k - NC];
          uint2 w = pw[kk * 128];
          acc.x = fmaf(hlo(w.x), a, acc.x); acc.y = fmaf(hhi(w.x), a, acc.y);
          acc.z = fmaf(hlo(w.y), a, acc.z); acc.w = fmaf(hhi(w.y), a, acc.w);
        }
        s_part4[qo * 128 + ogo] = acc;
      }
      __syncthreads();
      if (tid < NV) {
        float r = out_b[tid];
        #pragma unroll
        for (int q = 0; q < 8; ++q) r += s_part[q * NV + tid];
        out[((size_t)(b * NS + t)) * NV + tid] = r;
      }
      __syncthreads();
    }
  }

  if (SPLIT && tid >= 192 && tid < 512) {
    int i = tid - 192;
    hrv[(size_t)(b * NS + NS - 1) * KZ + i] = (i < NC) ? s_h[i] : s_rv[i - NC];
  }
}

// ---------------- Logits GEMM: 8192 x 512, K=320, fp16 weights ----------------
__launch_bounds__(512)
__global__ void ntm_logits(const float* __restrict__ ws, const float* __restrict__ out_b,
                           float* __restrict__ out)
{
  const uint2* OUT4 = ((const uint2*)ws) + U2_OUT;
  const float* hrv = ws + F_HRV;
  __shared__ float s_z[16 * 321];
  const int tid = threadIdx.x;
  const int r0 = blockIdx.x * 16;
  {
    int r = tid >> 5, i0 = tid & 31;
    const float* src = hrv + (size_t)(r0 + r) * KZ;
    for (int i = i0; i < KZ; i += 32) s_z[r * 321 + i] = src[i];
  }
  __syncthreads();
  const int og = tid & 127, rq = tid >> 7;
  const int rb = rq * 4;
  const uint2* pw = OUT4 + og;
  float4 a0 = {0,0,0,0}, a1 = a0, a2 = a0, a3 = a0;
  #pragma unroll 4
  for (int k = 0; k < KZ; ++k) {
    uint2 w = pw[k * 128];
    float w0 = hlo(w.x), w1 = hhi(w.x), w2 = hlo(w.y), w3 = hhi(w.y);
    float z0 = s_z[(rb + 0) * 321 + k], z1 = s_z[(rb + 1) * 321 + k];
    float z2 = s_z[(rb + 2) * 321 + k], z3 = s_z[(rb + 3) * 321 + k];
    a0.x = fmaf(w0, z0, a0.x); a0.y = fmaf(w1, z0, a0.y); a0.z = fmaf(w2, z0, a0.z); a0.w = fmaf(w3, z0, a0.w);
    a1.x = fmaf(w0, z1, a1.x); a1.y = fmaf(w1, z1, a1.y); a1.z = fmaf(w2, z1, a1.z); a1.w = fmaf(w3, z1, a1.w);
    a2.x = fmaf(w0, z2, a2.x); a2.y = fmaf(w1, z2, a2.y); a2.z = fmaf(w2, z2, a2.z); a2.w = fmaf(w3, z2, a2.w);
    a3.x = fmaf(w0, z3, a3.x); a3.y = fmaf(w1, z3, a3.y); a3.z = fmaf(w2, z3, a3.z); a3.w = fmaf(w3, z3, a3.w);
  }
  float4 ob = *(const float4*)(out_b + og * 4);
  a0.x += ob.x; a0.y += ob.y; a0.z += ob.z; a0.w += ob.w;
  a1.x += ob.x; a1.y += ob.y; a1.z += ob.z; a1.w += ob.w;
  a2.x += ob.x; a2.y += ob.y; a2.z += ob.z; a2.w += ob.w;
  a3.x += ob.x; a3.y += ob.y; a3.z += ob.z; a3.w += ob.w;
  float4* po = (float4*)(out + (size_t)(r0 + rb) * NV + og * 4);
  po[0 * (NV / 4)] = a0;
  po[1 * (NV / 4)] = a1;
  po[2 * (NV / 4)] = a2;
  po[3 * (NV / 4)] = a3;
}

extern "C" void kernel_launch(void* const* d_in, const int* in_sizes, int n_in,
                              void* d_out, int out_size, void* d_ws, size_t ws_size,
                              hipStream_t stream) {
  (void)in_sizes; (void)n_in; (void)out_size;
  const int*   x       = (const int*)  d_in[0];
  const float* emb     = (const float*)d_in[1];
  const float* W_ih    = (const float*)d_in[2];
  const float* W_hh    = (const float*)d_in[3];
  const float* b_ih    = (const float*)d_in[4];
  const float* b_hh    = (const float*)d_in[5];
  const float* key_W   = (const float*)d_in[6];
  const float* key_b   = (const float*)d_in[7];
  const float* beta_W  = (const float*)d_in[8];
  const float* beta_b  = (const float*)d_in[9];
  const float* gate_W  = (const float*)d_in[10];
  const float* gate_b  = (const float*)d_in[11];
  const float* shift_W = (const float*)d_in[12];
  const float* shift_b = (const float*)d_in[13];
  const float* gamma_W = (const float*)d_in[14];
  const float* gamma_b = (const float*)d_in[15];
  const float* erase_W = (const float*)d_in[16];
  const float* erase_b = (const float*)d_in[17];
  const float* add_W   = (const float*)d_in[18];
  const float* add_b   = (const float*)d_in[19];
  const float* out_W   = (const float*)d_in[20];
  const float* out_b   = (const float*)d_in[21];
  const float* mem_init= (const float*)d_in[22];
  float* ws  = (float*)d_ws;
  float* out = (float*)d_out;

  int prep_blocks = (PREP_ITEMS + 255) / 256;
  ntm_prep<<<prep_blocks, 256, 0, stream>>>(W_ih, W_hh, b_ih, b_hh, key_W, key_b,
      beta_W, beta_b, gate_W, gate_b, shift_W, shift_b, gamma_W, gamma_b,
      erase_W, erase_b, add_W, add_b, out_W, ws);

  bool split = (ws_size >= (size_t)WS_SPLIT_BYTES);
  if (split) {
    hipFuncSetAttribute((const void*)ntm_main<1>, hipFuncAttributeMaxDynamicSharedMemorySize,
                        SMEM_BYTES);
    ntm_main<1><<<NB, 1024, SMEM_BYTES, stream>>>(x, emb, out_b, mem_init, ws, out);
    ntm_logits<<<(NB * NS) / 16, 512, 0, stream>>>(ws, out_b, out);
  } else {
    hipFuncSetAttribute((const void*)ntm_main<0>, hipFuncAttributeMaxDynamicSharedMemorySize,
                        SMEM_BYTES);
    ntm_main<0><<<NB, 1024, SMEM_BYTES, stream>>>(x, emb, out_b, mem_init, ws, out);
  }
}

// Round 5
// 4975.932 us; speedup vs baseline: 2.4269x; 2.4269x over previous
//
#include <hip/hip_runtime.h>
#include <hip/hip_fp16.h>
#include <math.h>

// Problem constants
#define NB 64
#define NS 128
#define ND 128
#define NV 512
#define NC 256
#define NN 256
#define NM 64
#define NG 1024
#define KIH 192
#define KZ  320
#define KG  320      // in-loop gate K: 64 (rv) + 256 (h)
#define HST 208
#define MPAD 65

// ws layout (byte offsets, 16B aligned)
#define B_WG4   0u         // uint4[320*128]  gates weights [k][o/8], fp16 x8
#define N_WG4   40960
#define B_HWT4  655360u    // uint4[32*208]   head weights [kq][c], fp16 x8 (k = kq*8+e)
#define N_HWT4  6656
#define B_OUT2  761856u    // uint2[320*128]  out_W [k][o/4], fp16 x4
#define N_OUT2  40960
#define B_EMBG  1089536u   // float[512*1024] emb @ W_ih[:, :128]^T
#define B_BSUM  3186688u   // float[1024]
#define B_HB    3190784u   // float[208->256]
#define B_HRV   3191808u   // ushort[8192*320] fp16 h/rv history
#define WS_SPLIT_BYTES 8434688u
#define PREP1_ITEMS (N_WG4 + N_HWT4 + N_OUT2 + NG + HST)   // 89808

// LDS layout (floats)
#define L_MEM 0
#define L_ACT (NN*MPAD)          // 16640: act[0:64]=rv, act[64:320]=h
#define L_C   (L_ACT + KG)       // 16960
#define L_RW  (L_C + NC)         // 17216
#define L_W   (L_RW + NN)        // 17472
#define L_HD  (L_W + NN)         // 17728
#define L_SIM (L_HD + HST)       // 17936
#define L_PART (L_SIM + NN)      // 18192 (16B aligned)
#define SMEM_FLOATS (L_PART + 8192)   // 26384
#define SMEM_BYTES (SMEM_FLOATS * 4)  // 105536 B

__device__ __forceinline__ float sigf(float x) { return 1.0f / (1.0f + expf(-x)); }
__device__ __forceinline__ float splus(float x) { return (x > 20.f) ? x : log1pf(expf(x)); }

__device__ __forceinline__ float hlo(unsigned u) {
  unsigned short s = (unsigned short)(u & 0xffffu);
  _Float16 h; __builtin_memcpy(&h, &s, 2);
  return (float)h;
}
__device__ __forceinline__ float hhi(unsigned u) {
  unsigned short s = (unsigned short)(u >> 16);
  _Float16 h; __builtin_memcpy(&h, &s, 2);
  return (float)h;
}
__device__ __forceinline__ float h2f(unsigned short s) {
  _Float16 h; __builtin_memcpy(&h, &s, 2);
  return (float)h;
}
__device__ __forceinline__ unsigned short f2h(float f) {  // RNE
  _Float16 h = (_Float16)f;
  unsigned short s; __builtin_memcpy(&s, &h, 2);
  return s;
}

__device__ float head_w(int c, int k, const float* kW, const float* eW, const float* aW,
                        const float* sW, const float* bW, const float* gW, const float* gaW) {
  if (c < 64)  return kW[c * NC + k];
  if (c < 128) return eW[(c - 64) * NC + k];
  if (c < 192) return aW[(c - 128) * NC + k];
  if (c < 195) return sW[(c - 192) * NC + k];
  if (c == 195) return bW[k];
  if (c == 196) return gW[k];
  if (c == 197) return gaW[k];
  return 0.0f;
}

// ---------------- Prep 1: transpose + fp16-pack weights ----------------
__global__ void ntm_prep(const float* __restrict__ W_ih, const float* __restrict__ W_hh,
                         const float* __restrict__ b_ih, const float* __restrict__ b_hh,
                         const float* __restrict__ key_W, const float* __restrict__ key_b,
                         const float* __restrict__ beta_W, const float* __restrict__ beta_b,
                         const float* __restrict__ gate_W, const float* __restrict__ gate_b,
                         const float* __restrict__ shift_W, const float* __restrict__ shift_b,
                         const float* __restrict__ gamma_W, const float* __restrict__ gamma_b,
                         const float* __restrict__ erase_W, const float* __restrict__ erase_b,
                         const float* __restrict__ add_W, const float* __restrict__ add_b,
                         const float* __restrict__ out_W, char* __restrict__ ws)
{
  uint4* WG4  = (uint4*)(ws + B_WG4);
  uint4* HWT4 = (uint4*)(ws + B_HWT4);
  uint2* OUT2 = (uint2*)(ws + B_OUT2);
  float* bsum = (float*)(ws + B_BSUM);
  float* hb   = (float*)(ws + B_HB);

  for (int idx = blockIdx.x * blockDim.x + threadIdx.x; idx < PREP1_ITEMS;
       idx += gridDim.x * blockDim.x) {
    if (idx < N_WG4) {
      int k = idx >> 7, og = idx & 127;
      float v[8];
      #pragma unroll
      for (int j = 0; j < 8; ++j) {
        int o = og * 8 + j;
        v[j] = (k < 64) ? W_ih[o * KIH + ND + k] : W_hh[o * NC + (k - 64)];
      }
      uint4 p;
      p.x = (unsigned)f2h(v[0]) | ((unsigned)f2h(v[1]) << 16);
      p.y = (unsigned)f2h(v[2]) | ((unsigned)f2h(v[3]) << 16);
      p.z = (unsigned)f2h(v[4]) | ((unsigned)f2h(v[5]) << 16);
      p.w = (unsigned)f2h(v[6]) | ((unsigned)f2h(v[7]) << 16);
      WG4[idx] = p;
    } else if (idx < N_WG4 + N_HWT4) {
      int i = idx - N_WG4;
      int kq = i / HST, c = i % HST;
      float v[8];
      #pragma unroll
      for (int j = 0; j < 8; ++j)
        v[j] = head_w(c, kq * 8 + j, key_W, erase_W, add_W, shift_W, beta_W, gate_W, gamma_W);
      uint4 p;
      p.x = (unsigned)f2h(v[0]) | ((unsigned)f2h(v[1]) << 16);
      p.y = (unsigned)f2h(v[2]) | ((unsigned)f2h(v[3]) << 16);
      p.z = (unsigned)f2h(v[4]) | ((unsigned)f2h(v[5]) << 16);
      p.w = (unsigned)f2h(v[6]) | ((unsigned)f2h(v[7]) << 16);
      HWT4[kq * HST + c] = p;
    } else if (idx < N_WG4 + N_HWT4 + N_OUT2) {
      int i = idx - N_WG4 - N_HWT4;
      int k = i >> 7, og = i & 127;
      float v[4];
      #pragma unroll
      for (int j = 0; j < 4; ++j) v[j] = out_W[(og * 4 + j) * KZ + k];
      uint2 p;
      p.x = (unsigned)f2h(v[0]) | ((unsigned)f2h(v[1]) << 16);
      p.y = (unsigned)f2h(v[2]) | ((unsigned)f2h(v[3]) << 16);
      OUT2[i] = p;
    } else if (idx < N_WG4 + N_HWT4 + N_OUT2 + NG) {
      int o = idx - N_WG4 - N_HWT4 - N_OUT2;
      bsum[o] = b_ih[o] + b_hh[o];
    } else {
      int c = idx - N_WG4 - N_HWT4 - N_OUT2 - NG;
      float v;
      if (c < 64)       v = key_b[c];
      else if (c < 128) v = erase_b[c - 64];
      else if (c < 192) v = add_b[c - 128];
      else if (c < 195) v = shift_b[c - 192];
      else if (c == 195) v = beta_b[0];
      else if (c == 196) v = gate_b[0];
      else               v = gamma_b[0];
      hb[c] = v;
    }
  }
}

// ---------------- Prep 2: embG[v][o] = sum_{k<128} emb[v][k] * W_ih[o][k] ----------------
__global__ void ntm_prep_embg(const float* __restrict__ emb, const float* __restrict__ W_ih,
                              char* __restrict__ ws)
{
  float* embG = (float*)(ws + B_EMBG);
  __shared__ float s_e[ND];
  int v = blockIdx.x, tid = threadIdx.x;
  if (tid < ND) s_e[tid] = emb[v * ND + tid];
  __syncthreads();
  #pragma unroll
  for (int q = 0; q < 4; ++q) {
    int o = tid + q * 256;
    const float* wp = W_ih + o * KIH;
    float acc = 0.f;
    #pragma unroll 8
    for (int k = 0; k < ND; ++k) acc = fmaf(s_e[k], wp[k], acc);
    embG[v * NG + o] = acc;
  }
}

// ---------------- Main: one block per batch element, full scan ----------------
template <int SPLIT>
__launch_bounds__(1024, 1)
__global__ void ntm_main(const int* __restrict__ x, const float* __restrict__ out_b,
                         const float* __restrict__ mem_init, char* __restrict__ ws,
                         float* __restrict__ out)
{
  const int b = blockIdx.x;
  const int tid = threadIdx.x;
  const uint4* WG4  = (const uint4*)(ws + B_WG4);
  const uint4* HWT4 = (const uint4*)(ws + B_HWT4);
  const uint2* OUT2 = (const uint2*)(ws + B_OUT2);
  const float* embG = (const float*)(ws + B_EMBG);
  const float* bsum = (const float*)(ws + B_BSUM);
  const float* hb   = (const float*)(ws + B_HB);
  unsigned short* hrv16 = (unsigned short*)(ws + B_HRV);

  extern __shared__ float sm[];
  float* s_mem = sm + L_MEM;
  float* s_act = sm + L_ACT;     // [0:64]=rv, [64:320]=h
  float* s_c   = sm + L_C;
  float* s_rw  = sm + L_RW;
  float* s_w   = sm + L_W;
  float* s_hd  = sm + L_HD;
  float* s_sim = sm + L_SIM;
  float* s_part = sm + L_PART;
  float4* s_part4 = (float4*)s_part;

  // per-thread constant mappings
  const int og2 = tid & 127, q2 = tid >> 7;          // phase 2: 8 outs x 40 k
  const int c4 = tid % HST, q4 = tid / HST;          // phase 4 (tid<832): 1 col x 64 k
  const int n6 = tid >> 2, q6 = tid & 3;             // phase 6
  const int m8 = tid & 63, q8 = tid >> 6;            // phase 8

  // scalar preloads
  float bs0 = 0.f, bs1 = 0.f, bs2 = 0.f, bs3 = 0.f, hbv = 0.f;
  if (tid < NC) {
    bs0 = bsum[tid]; bs1 = bsum[NC + tid]; bs2 = bsum[2 * NC + tid]; bs3 = bsum[3 * NC + tid];
    hbv = hb[tid];
  }

  // init state
  for (int i = tid; i < NN * NM; i += 1024) {
    int n = i >> 6, m = i & 63;
    s_mem[n * MPAD + m] = mem_init[b * NN * NM + i];
  }
  if (tid < KG) s_act[tid] = 0.f;
  if (tid < NC) s_c[tid] = 0.f;
  if (tid < NN) s_rw[tid] = 0.f;
  __syncthreads();

  for (int t = 0; t < NS; ++t) {
    // ---- phase A (no barrier): embG prefetch, HWT preload, hrv store of t-1 ----
    int tok = x[b * NS + t];
    float eg0 = 0.f, eg1 = 0.f, eg2 = 0.f, eg3 = 0.f;
    if (tid < NC) {
      const float* ep = embG + (size_t)tok * NG;
      eg0 = ep[tid]; eg1 = ep[NC + tid]; eg2 = ep[2 * NC + tid]; eg3 = ep[3 * NC + tid];
    }
    uint4 hwtp[8];
    if (tid < 832) {
      const uint4* hp = HWT4 + q4 * 8 * HST + c4;
      #pragma unroll
      for (int j = 0; j < 8; ++j) hwtp[j] = hp[j * HST];
    }
    if (SPLIT && t > 0 && tid >= 192 && tid < 512) {
      int i = tid - 192;
      float v = (i < NC) ? s_act[64 + i] : s_act[i - NC];
      hrv16[(size_t)(b * NS + (t - 1)) * KZ + i] = f2h(v);
    }

    // ---- phase 2: gate partials (8 outs x 40 k per thread, uint4 weight loads) ----
    {
      float acc[8] = {0.f, 0.f, 0.f, 0.f, 0.f, 0.f, 0.f, 0.f};
      const uint4* pw = WG4 + (q2 * 40) * 128 + og2;
      const float* ap = s_act + q2 * 40;
      #pragma unroll
      for (int kk = 0; kk < 40; ++kk) {
        uint4 w = pw[kk * 128];
        float a = ap[kk];
        acc[0] = fmaf(hlo(w.x), a, acc[0]); acc[1] = fmaf(hhi(w.x), a, acc[1]);
        acc[2] = fmaf(hlo(w.y), a, acc[2]); acc[3] = fmaf(hhi(w.y), a, acc[3]);
        acc[4] = fmaf(hlo(w.z), a, acc[4]); acc[5] = fmaf(hhi(w.z), a, acc[5]);
        acc[6] = fmaf(hlo(w.w), a, acc[6]); acc[7] = fmaf(hhi(w.w), a, acc[7]);
      }
      float4 lo = {acc[0], acc[1], acc[2], acc[3]};
      float4 hi = {acc[4], acc[5], acc[6], acc[7]};
      s_part4[q2 * 256 + og2 * 2] = lo;
      s_part4[q2 * 256 + og2 * 2 + 1] = hi;
    }
    __syncthreads();  // S2

    // ---- phase 3: combine gates (+embG row) + LSTM cell (torch order i,f,g,o) ----
    if (tid < NC) {
      float gi = bs0 + eg0, gf = bs1 + eg1, gg = bs2 + eg2, go = bs3 + eg3;
      #pragma unroll
      for (int q = 0; q < 8; ++q) {
        const float* pp = s_part + q * NG;
        gi += pp[tid]; gf += pp[NC + tid]; gg += pp[2 * NC + tid]; go += pp[3 * NC + tid];
      }
      float cn = sigf(gf) * s_c[tid] + sigf(gi) * tanhf(gg);
      s_c[tid] = cn;
      s_act[64 + tid] = sigf(go) * tanhf(cn);   // h
    }
    __syncthreads();  // S3

    // ---- phase 4: head-linear partials from preloaded regs (208 cols x 4 k-chunks) ----
    if (tid < 832) {
      float acc = 0.f;
      const float* hp = s_act + 64 + q4 * 64;
      #pragma unroll
      for (int j = 0; j < 8; ++j) {
        uint4 u = hwtp[j];
        acc = fmaf(hlo(u.x), hp[j * 8 + 0], acc); acc = fmaf(hhi(u.x), hp[j * 8 + 1], acc);
        acc = fmaf(hlo(u.y), hp[j * 8 + 2], acc); acc = fmaf(hhi(u.y), hp[j * 8 + 3], acc);
        acc = fmaf(hlo(u.z), hp[j * 8 + 4], acc); acc = fmaf(hhi(u.z), hp[j * 8 + 5], acc);
        acc = fmaf(hlo(u.w), hp[j * 8 + 6], acc); acc = fmaf(hhi(u.w), hp[j * 8 + 7], acc);
      }
      s_part[q4 * HST + c4] = acc;
    }
    __syncthreads();  // S4

    // ---- phase 5: combine + activations (wave-aligned) ----
    if (tid < 256) {
      float val = 0.f;
      if (tid < HST) {
        val = hbv;
        #pragma unroll
        for (int q = 0; q < 4; ++q) val += s_part[q * HST + tid];
      }
      int wv = tid >> 6;
      if (wv == 0) {            // key l2-normalize
        float ss = val * val;
        for (int off = 32; off; off >>= 1) ss += __shfl_xor(ss, off);
        s_hd[tid] = val / fmaxf(sqrtf(ss), 1e-12f);
      } else if (wv == 1) {     // erase: sigmoid
        s_hd[tid] = sigf(val);
      } else if (wv == 2) {     // add: tanh
        s_hd[tid] = tanhf(val);
      } else {                  // wave 3: shift softmax + scalars
        int l = tid & 63;
        float a0 = __shfl(val, 0), a1 = __shfl(val, 1), a2 = __shfl(val, 2);
        float mx = fmaxf(a0, fmaxf(a1, a2));
        float e0 = expf(a0 - mx), e1 = expf(a1 - mx), e2 = expf(a2 - mx);
        float ss = e0 + e1 + e2;
        float r = 0.f;
        if (l == 0) r = e0 / ss;
        else if (l == 1) r = e1 / ss;
        else if (l == 2) r = e2 / ss;
        else if (l == 3) r = splus(val);          // beta  (col 195)
        else if (l == 4) r = sigf(val);           // gate  (col 196)
        else if (l == 5) r = 1.0f + splus(val);   // gamma (col 197)
        if (l < 16) s_hd[192 + l] = r;
      }
    }
    __syncthreads();  // S5

    // ---- phase 6: cosine sim (4 lanes per memory row) ----
    {
      const float* mrow = s_mem + n6 * MPAD + q6 * 16;
      const float* kp = s_hd + q6 * 16;
      float dot = 0.f, sq = 0.f;
      #pragma unroll
      for (int i = 0; i < 16; ++i) {
        float mv = mrow[i];
        dot = fmaf(mv, kp[i], dot);
        sq  = fmaf(mv, mv, sq);
      }
      dot += __shfl_xor(dot, 1); dot += __shfl_xor(dot, 2);
      sq  += __shfl_xor(sq, 1);  sq  += __shfl_xor(sq, 2);
      if (q6 == 0) s_sim[n6] = dot / fmaxf(sqrtf(sq), 1e-12f);
    }
    __syncthreads();  // S6

    // ---- phase 7: full addressing chain in one wave (4 slots/lane) ----
    if (tid < 64) {
      int l = tid;
      float beta = s_hd[195], gate = s_hd[196], gamma = s_hd[197];
      float sh0 = s_hd[192], sh1 = s_hd[193], sh2 = s_hd[194];
      float v0 = beta * s_sim[l], v1 = beta * s_sim[64 + l];
      float v2 = beta * s_sim[128 + l], v3 = beta * s_sim[192 + l];
      float mx = fmaxf(fmaxf(v0, v1), fmaxf(v2, v3));
      for (int off = 32; off; off >>= 1) mx = fmaxf(mx, __shfl_xor(mx, off));
      float e0 = expf(v0 - mx), e1 = expf(v1 - mx), e2 = expf(v2 - mx), e3 = expf(v3 - mx);
      float s = e0 + e1 + e2 + e3;
      for (int off = 32; off; off >>= 1) s += __shfl_xor(s, off);
      float inv = 1.0f / s, omg = 1.0f - gate;
      float wg[4];
      wg[0] = gate * e0 * inv + omg * s_rw[l];
      wg[1] = gate * e1 * inv + omg * s_rw[64 + l];
      wg[2] = gate * e2 * inv + omg * s_rw[128 + l];
      wg[3] = gate * e3 * inv + omg * s_rw[192 + l];
      float p[4]; float ps = 0.f;
      #pragma unroll
      for (int j = 0; j < 4; ++j) {
        float cu = (l == 0) ? wg[(j + 1) & 3] : wg[j];
        float up = __shfl(cu, (l + 1) & 63);
        float cd = (l == 63) ? wg[(j + 3) & 3] : wg[j];
        float dn = __shfl(cd, (l + 63) & 63);
        float wn = fmaf(sh0, up, fmaf(sh1, wg[j], sh2 * dn));
        p[j] = powf(wn, gamma);
        ps += p[j];
      }
      for (int off = 32; off; off >>= 1) ps += __shfl_xor(ps, off);
      float invp = 1.0f / ps;
      #pragma unroll
      for (int j = 0; j < 4; ++j) {
        float wv = p[j] * invp;
        s_w[l + 64 * j] = wv;
        s_rw[l + 64 * j] = wv;
      }
    }
    __syncthreads();  // S7

    // ---- phase 8: rv partials = w @ mem (16 n-chunks x 64 m) ----
    {
      float acc = 0.f;
      int n0 = q8 * 16;
      #pragma unroll
      for (int i = 0; i < 16; ++i) {
        int n = n0 + i;
        acc = fmaf(s_w[n], s_mem[n * MPAD + m8], acc);
      }
      s_part[q8 * 64 + m8] = acc;
    }
    __syncthreads();  // S8

    // ---- phase 9: rv combine (into s_act[0:64]) + memory update ----
    if (tid < NM) {
      float acc = 0.f;
      #pragma unroll
      for (int q = 0; q < 16; ++q) acc += s_part[q * 64 + tid];
      s_act[tid] = acc;
    }
    for (int i = tid; i < NN * NM; i += 1024) {
      int n = i >> 6, m = i & 63;
      float wv = s_w[n];
      float cur = s_mem[n * MPAD + m];
      s_mem[n * MPAD + m] = cur * (1.f - wv * s_hd[64 + m]) + wv * s_hd[128 + m];
    }
    __syncthreads();  // S9

    if (!SPLIT) {
      // fused logits fallback: 4 cols x 8 k-chunks of 40 per thread (streams OUT2)
      {
        int ogo = tid & 127, qo = tid >> 7;
        const uint2* pw = OUT2 + (qo * 40) * 128 + ogo;
        float4 acc = {0.f, 0.f, 0.f, 0.f};
        #pragma unroll 8
        for (int kk = 0; kk < 40; ++kk) {
          int k = qo * 40 + kk;
          float a = (k < NC) ? s_act[64 + k] : s_act[k - NC];
          uint2 w = pw[kk * 128];
          acc.x = fmaf(hlo(w.x), a, acc.x); acc.y = fmaf(hhi(w.x), a, acc.y);
          acc.z = fmaf(hlo(w.y), a, acc.z); acc.w = fmaf(hhi(w.y), a, acc.w);
        }
        s_part4[qo * 128 + ogo] = acc;
      }
      __syncthreads();
      if (tid < NV) {
        float r = out_b[tid];
        #pragma unroll
        for (int q = 0; q < 8; ++q) r += s_part[q * NV + tid];
        out[((size_t)(b * NS + t)) * NV + tid] = r;
      }
      __syncthreads();
    }
  }

  if (SPLIT && tid >= 192 && tid < 512) {
    int i = tid - 192;
    float v = (i < NC) ? s_act[64 + i] : s_act[i - NC];
    hrv16[(size_t)(b * NS + NS - 1) * KZ + i] = f2h(v);
  }
}

// ---------------- Logits GEMM: 8192 x 512, K=320, fp16 weights + fp16 acts ----------------
__launch_bounds__(512)
__global__ void ntm_logits(const char* __restrict__ ws, const float* __restrict__ out_b,
                           float* __restrict__ out)
{
  const uint2* OUT2 = (const uint2*)(ws + B_OUT2);
  const unsigned short* hrv16 = (const unsigned short*)(ws + B_HRV);
  __shared__ float s_z[16 * 321];
  const int tid = threadIdx.x;
  const int r0 = blockIdx.x * 16;
  {
    int r = tid >> 5, i0 = tid & 31;
    const unsigned short* src = hrv16 + (size_t)(r0 + r) * KZ;
    for (int i = i0; i < KZ; i += 32) s_z[r * 321 + i] = h2f(src[i]);
  }
  __syncthreads();
  const int og = tid & 127, rq = tid >> 7;
  const int rb = rq * 4;
  const uint2* pw = OUT2 + og;
  float4 a0 = {0,0,0,0}, a1 = a0, a2 = a0, a3 = a0;
  #pragma unroll 4
  for (int k = 0; k < KZ; ++k) {
    uint2 w = pw[k * 128];
    float w0 = hlo(w.x), w1 = hhi(w.x), w2 = hlo(w.y), w3 = hhi(w.y);
    float z0 = s_z[(rb + 0) * 321 + k], z1 = s_z[(rb + 1) * 321 + k];
    float z2 = s_z[(rb + 2) * 321 + k], z3 = s_z[(rb + 3) * 321 + k];
    a0.x = fmaf(w0, z0, a0.x); a0.y = fmaf(w1, z0, a0.y); a0.z = fmaf(w2, z0, a0.z); a0.w = fmaf(w3, z0, a0.w);
    a1.x = fmaf(w0, z1, a1.x); a1.y = fmaf(w1, z1, a1.y); a1.z = fmaf(w2, z1, a1.z); a1.w = fmaf(w3, z1, a1.w);
    a2.x = fmaf(w0, z2, a2.x); a2.y = fmaf(w1, z2, a2.y); a2.z = fmaf(w2, z2, a2.z); a2.w = fmaf(w3, z2, a2.w);
    a3.x = fmaf(w0, z3, a3.x); a3.y = fmaf(w1, z3, a3.y); a3.z = fmaf(w2, z3, a3.z); a3.w = fmaf(w3, z3, a3.w);
  }
  float4 ob = *(const float4*)(out_b + og * 4);
  a0.x += ob.x; a0.y += ob.y; a0.z += ob.z; a0.w += ob.w;
  a1.x += ob.x; a1.y += ob.y; a1.z += ob.z; a1.w += ob.w;
  a2.x += ob.x; a2.y += ob.y; a2.z += ob.z; a2.w += ob.w;
  a3.x += ob.x; a3.y += ob.y; a3.z += ob.z; a3.w += ob.w;
  float4* po = (float4*)(out + (size_t)(r0 + rb) * NV + og * 4);
  po[0 * (NV / 4)] = a0;
  po[1 * (NV / 4)] = a1;
  po[2 * (NV / 4)] = a2;
  po[3 * (NV / 4)] = a3;
}

extern "C" void kernel_launch(void* const* d_in, const int* in_sizes, int n_in,
                              void* d_out, int out_size, void* d_ws, size_t ws_size,
                              hipStream_t stream) {
  (void)in_sizes; (void)n_in; (void)out_size;
  const int*   x       = (const int*)  d_in[0];
  const float* emb     = (const float*)d_in[1];
  const float* W_ih    = (const float*)d_in[2];
  const float* W_hh    = (const float*)d_in[3];
  const float* b_ih    = (const float*)d_in[4];
  const float* b_hh    = (const float*)d_in[5];
  const float* key_W   = (const float*)d_in[6];
  const float* key_b   = (const float*)d_in[7];
  const float* beta_W  = (const float*)d_in[8];
  const float* beta_b  = (const float*)d_in[9];
  const float* gate_W  = (const float*)d_in[10];
  const float* gate_b  = (const float*)d_in[11];
  const float* shift_W = (const float*)d_in[12];
  const float* shift_b = (const float*)d_in[13];
  const float* gamma_W = (const float*)d_in[14];
  const float* gamma_b = (const float*)d_in[15];
  const float* erase_W = (const float*)d_in[16];
  const float* erase_b = (const float*)d_in[17];
  const float* add_W   = (const float*)d_in[18];
  const float* add_b   = (const float*)d_in[19];
  const float* out_W   = (const float*)d_in[20];
  const float* out_b   = (const float*)d_in[21];
  const float* mem_init= (const float*)d_in[22];
  char* ws   = (char*)d_ws;
  float* out = (float*)d_out;

  int prep_blocks = (PREP1_ITEMS + 255) / 256;
  ntm_prep<<<prep_blocks, 256, 0, stream>>>(W_ih, W_hh, b_ih, b_hh, key_W, key_b,
      beta_W, beta_b, gate_W, gate_b, shift_W, shift_b, gamma_W, gamma_b,
      erase_W, erase_b, add_W, add_b, out_W, ws);
  ntm_prep_embg<<<NV, 256, 0, stream>>>(emb, W_ih, ws);

  bool split = (ws_size >= (size_t)WS_SPLIT_BYTES);
  if (split) {
    hipFuncSetAttribute((const void*)ntm_main<1>, hipFuncAttributeMaxDynamicSharedMemorySize,
                        SMEM_BYTES);
    ntm_main<1><<<NB, 1024, SMEM_BYTES, stream>>>(x, out_b, mem_init, ws, out);
    ntm_logits<<<(NB * NS) / 16, 512, 0, stream>>>(ws, out_b, out);
  } else {
    hipFuncSetAttribute((const void*)ntm_main<0>, hipFuncAttributeMaxDynamicSharedMemorySize,
                        SMEM_BYTES);
    ntm_main<0><<<NB, 1024, SMEM_BYTES, stream>>>(x, out_b, mem_init, ws, out);
  }
}

// Round 6
// 4318.179 us; speedup vs baseline: 2.7966x; 1.1523x over previous
//
#include <hip/hip_runtime.h>
#include <hip/hip_fp16.h>
#include <math.h>

// Problem constants
#define NB 64
#define NS 128
#define ND 128
#define NV 512
#define NC 256
#define NN 256
#define NM 64
#define NG 1024
#define KIH 192
#define KZ  320
#define KG  320      // in-loop gate K: 64 (rv) + 256 (h)
#define HST 208
#define MPAD 65

// ws layout (byte offsets, 16B aligned)
#define B_WGD   0u         // uint4[40*1024]  gate weights [kq][o], 8 consecutive k-halves per uint4
#define N_WGD   40960
#define B_HWT   655360u    // uint4[32*208]   head weights [kq][c], 8 consecutive k-halves
#define N_HWT   6656
#define B_OUT2  761856u    // uint2[320*128]  out_W [k][og], 4 outs per uint2 (fp16)
#define N_OUT2  40960
#define B_EMBG  1089536u   // float[512*1024] emb @ W_ih[:, :128]^T
#define B_BSUM  3186688u   // float[1024]
#define B_HB    3190784u   // float[208->256]
#define B_HRV   3191808u   // uint[8192*160] packed fp16 [h(128u), rv(32u)] history
#define WS_SPLIT_BYTES 8434688u
#define PREP1_ITEMS (N_WGD + N_HWT + N_OUT2 + NG + HST)   // 89808

// LDS layout (floats)
#define L_MEM 0
#define L_ACT (NN*MPAD)          // 16640: 160 uints packed fp16: [rv 32u][h 128u]
#define L_C   (L_ACT + KG)       // fp32 cell state (256)
#define L_RW  (L_C + NC)
#define L_W   (L_RW + NN)
#define L_HD  (L_W + NN)
#define L_SIM (L_HD + HST)
#define L_PART (L_SIM + NN)      // 8192 floats (16B aligned)
#define L_TOK (L_PART + 8192)
#define SMEM_FLOATS (L_TOK + 128)
#define SMEM_BYTES (SMEM_FLOATS * 4)   // 106048 B

__device__ __forceinline__ float sigf(float x) { return 1.0f / (1.0f + expf(-x)); }
__device__ __forceinline__ float splus(float x) { return (x > 20.f) ? x : log1pf(expf(x)); }

__device__ __forceinline__ float hlo(unsigned u) {
  unsigned short s = (unsigned short)(u & 0xffffu);
  _Float16 h; __builtin_memcpy(&h, &s, 2);
  return (float)h;
}
__device__ __forceinline__ float hhi(unsigned u) {
  unsigned short s = (unsigned short)(u >> 16);
  _Float16 h; __builtin_memcpy(&h, &s, 2);
  return (float)h;
}
__device__ __forceinline__ unsigned short f2h(float f) {  // RNE
  _Float16 h = (_Float16)f;
  unsigned short s; __builtin_memcpy(&s, &h, 2);
  return s;
}
__device__ __forceinline__ unsigned packh(float a, float b) {
  return (unsigned)f2h(a) | ((unsigned)f2h(b) << 16);
}

typedef _Float16 half2v __attribute__((ext_vector_type(2)));

// fp16-pair dot with fp32 accumulate (v_dot2_f32_f16)
__device__ __forceinline__ float dot2(unsigned w, unsigned a, float acc) {
#if __has_builtin(__builtin_amdgcn_fdot2)
  half2v wv, av;
  __builtin_memcpy(&wv, &w, 4);
  __builtin_memcpy(&av, &a, 4);
  return __builtin_amdgcn_fdot2(wv, av, acc, false);
#else
  acc = fmaf(hlo(w), hlo(a), acc);
  return fmaf(hhi(w), hhi(a), acc);
#endif
}

__device__ float head_w(int c, int k, const float* kW, const float* eW, const float* aW,
                        const float* sW, const float* bW, const float* gW, const float* gaW) {
  if (c < 64)  return kW[c * NC + k];
  if (c < 128) return eW[(c - 64) * NC + k];
  if (c < 192) return aW[(c - 128) * NC + k];
  if (c < 195) return sW[(c - 192) * NC + k];
  if (c == 195) return bW[k];
  if (c == 196) return gW[k];
  if (c == 197) return gaW[k];
  return 0.0f;
}

// ---------------- Prep 1: transpose + fp16-pack weights ----------------
__global__ void ntm_prep(const float* __restrict__ W_ih, const float* __restrict__ W_hh,
                         const float* __restrict__ b_ih, const float* __restrict__ b_hh,
                         const float* __restrict__ key_W, const float* __restrict__ key_b,
                         const float* __restrict__ beta_W, const float* __restrict__ beta_b,
                         const float* __restrict__ gate_W, const float* __restrict__ gate_b,
                         const float* __restrict__ shift_W, const float* __restrict__ shift_b,
                         const float* __restrict__ gamma_W, const float* __restrict__ gamma_b,
                         const float* __restrict__ erase_W, const float* __restrict__ erase_b,
                         const float* __restrict__ add_W, const float* __restrict__ add_b,
                         const float* __restrict__ out_W, char* __restrict__ ws)
{
  uint4* WGD  = (uint4*)(ws + B_WGD);
  uint4* HWT  = (uint4*)(ws + B_HWT);
  uint2* OUT2 = (uint2*)(ws + B_OUT2);
  float* bsum = (float*)(ws + B_BSUM);
  float* hb   = (float*)(ws + B_HB);

  for (int idx = blockIdx.x * blockDim.x + threadIdx.x; idx < PREP1_ITEMS;
       idx += gridDim.x * blockDim.x) {
    if (idx < N_WGD) {
      // WGD[kq*1024 + o]: halves j -> k = kq*8+j; k<64: rv rows (W_ih col 128+k), else h rows
      int kq = idx >> 10, o = idx & 1023;
      float v[8];
      #pragma unroll
      for (int j = 0; j < 8; ++j) {
        int k = kq * 8 + j;
        v[j] = (k < 64) ? W_ih[o * KIH + ND + k] : W_hh[o * NC + (k - 64)];
      }
      uint4 p;
      p.x = packh(v[0], v[1]); p.y = packh(v[2], v[3]);
      p.z = packh(v[4], v[5]); p.w = packh(v[6], v[7]);
      WGD[idx] = p;
    } else if (idx < N_WGD + N_HWT) {
      int i = idx - N_WGD;
      int kq = i / HST, c = i % HST;
      float v[8];
      #pragma unroll
      for (int j = 0; j < 8; ++j)
        v[j] = head_w(c, kq * 8 + j, key_W, erase_W, add_W, shift_W, beta_W, gate_W, gamma_W);
      uint4 p;
      p.x = packh(v[0], v[1]); p.y = packh(v[2], v[3]);
      p.z = packh(v[4], v[5]); p.w = packh(v[6], v[7]);
      HWT[kq * HST + c] = p;
    } else if (idx < N_WGD + N_HWT + N_OUT2) {
      int i = idx - N_WGD - N_HWT;
      int k = i >> 7, og = i & 127;
      float v[4];
      #pragma unroll
      for (int j = 0; j < 4; ++j) v[j] = out_W[(og * 4 + j) * KZ + k];
      uint2 p;
      p.x = packh(v[0], v[1]); p.y = packh(v[2], v[3]);
      OUT2[i] = p;
    } else if (idx < N_WGD + N_HWT + N_OUT2 + NG) {
      int o = idx - N_WGD - N_HWT - N_OUT2;
      bsum[o] = b_ih[o] + b_hh[o];
    } else {
      int c = idx - N_WGD - N_HWT - N_OUT2 - NG;
      float v;
      if (c < 64)       v = key_b[c];
      else if (c < 128) v = erase_b[c - 64];
      else if (c < 192) v = add_b[c - 128];
      else if (c < 195) v = shift_b[c - 192];
      else if (c == 195) v = beta_b[0];
      else if (c == 196) v = gate_b[0];
      else               v = gamma_b[0];
      hb[c] = v;
    }
  }
}

// ---------------- Prep 2: embG[v][o] = sum_{k<128} emb[v][k] * W_ih[o][k] ----------------
__global__ void ntm_prep_embg(const float* __restrict__ emb, const float* __restrict__ W_ih,
                              char* __restrict__ ws)
{
  float* embG = (float*)(ws + B_EMBG);
  __shared__ float s_e[ND];
  int v = blockIdx.x, tid = threadIdx.x;
  if (tid < ND) s_e[tid] = emb[v * ND + tid];
  __syncthreads();
  #pragma unroll
  for (int q = 0; q < 4; ++q) {
    int o = tid + q * 256;
    const float* wp = W_ih + o * KIH;
    float acc = 0.f;
    #pragma unroll 8
    for (int k = 0; k < ND; ++k) acc = fmaf(s_e[k], wp[k], acc);
    embG[v * NG + o] = acc;
  }
}

// ---------------- Main: one block per batch element, full scan ----------------
template <int SPLIT>
__launch_bounds__(1024, 1)
__global__ void ntm_main(const int* __restrict__ x, const float* __restrict__ out_b,
                         const float* __restrict__ mem_init, char* __restrict__ ws,
                         float* __restrict__ out)
{
  const int b = blockIdx.x;
  const int tid = threadIdx.x;
  const uint4* WGD  = (const uint4*)(ws + B_WGD);
  const uint4* HWT  = (const uint4*)(ws + B_HWT);
  const uint2* OUT2 = (const uint2*)(ws + B_OUT2);
  const float* embG = (const float*)(ws + B_EMBG);
  const float* bsum = (const float*)(ws + B_BSUM);
  const float* hb   = (const float*)(ws + B_HB);
  unsigned* hrv32 = (unsigned*)(ws + B_HRV);

  extern __shared__ float sm[];
  float* s_mem = sm + L_MEM;
  unsigned* s_actp = (unsigned*)(sm + L_ACT);     // [0:32)=rv pairs, [32:160)=h pairs
  const uint4* s_actp4 = (const uint4*)s_actp;
  float* s_c   = sm + L_C;
  float* s_rw  = sm + L_RW;
  float* s_w   = sm + L_W;
  float* s_hd  = sm + L_HD;
  float* s_sim = sm + L_SIM;
  float* s_part = sm + L_PART;
  int*   s_tok = (int*)(sm + L_TOK);

  // per-thread constant mappings
  const int og2 = tid & 127, q2 = tid >> 7;          // phase 2: outs o = og2+128j, k-chunk q2 (40 halves)
  const int c4 = tid % HST, q4 = tid / HST;          // phase 4 (tid<832): col c4, k-chunk q4 (64 halves)
  const int n6 = tid >> 2, q6 = tid & 3;             // phase 6
  const int m8 = tid & 63, q8 = tid >> 6;            // phase 8

  // scalar preloads (small named values only — arrays across barriers spill!)
  float2 bsq0 = {0.f, 0.f}, bsq1 = bsq0, bsq2 = bsq0, bsq3 = bsq0;
  if (tid < 128) {
    bsq0 = *(const float2*)(bsum + 2 * tid);
    bsq1 = *(const float2*)(bsum + NC + 2 * tid);
    bsq2 = *(const float2*)(bsum + 2 * NC + 2 * tid);
    bsq3 = *(const float2*)(bsum + 3 * NC + 2 * tid);
  }
  float hbv = (tid < NC) ? hb[tid] : 0.f;

  // init state
  for (int i = tid; i < NN * NM; i += 1024) {
    int n = i >> 6, m = i & 63;
    s_mem[n * MPAD + m] = mem_init[b * NN * NM + i];
  }
  if (tid < 160) s_actp[tid] = 0u;
  if (tid < NC) s_c[tid] = 0.f;
  if (tid < NN) s_rw[tid] = 0.f;
  if (tid < NS) s_tok[tid] = x[b * NS + tid];
  __syncthreads();

  for (int t = 0; t < NS; ++t) {
    int tok = s_tok[t];
    // ---- phase A (no barrier): embG prefetch for phase 3; hrv store of step t-1 ----
    float2 eg0 = {0.f, 0.f}, eg1 = eg0, eg2 = eg0, eg3 = eg0;
    if (tid < 128) {
      const float* ep = embG + (size_t)tok * NG + 2 * tid;
      eg0 = *(const float2*)(ep);
      eg1 = *(const float2*)(ep + NC);
      eg2 = *(const float2*)(ep + 2 * NC);
      eg3 = *(const float2*)(ep + 3 * NC);
    }
    if (SPLIT && t > 0 && tid < 160) {
      // hrv row layout: [h pairs 0..127][rv pairs 128..159]
      unsigned v = (tid < 128) ? s_actp[32 + tid] : s_actp[tid - 128];
      hrv32[(size_t)(b * NS + (t - 1)) * 160 + tid] = v;
    }

    // ---- phase 2: full-K gate dot for 8 outputs (o = og2 + 128j), k-chunk q2 ----
    {
      float a0 = 0.f, a1 = 0.f, a2 = 0.f, a3 = 0.f, a4 = 0.f, a5 = 0.f, a6 = 0.f, a7 = 0.f;
      #pragma unroll
      for (int m = 0; m < 5; ++m) {
        uint4 av = s_actp4[q2 * 5 + m];
        const uint4* pw = WGD + (size_t)(q2 * 5 + m) * 1024 + og2;
        uint4 w0 = pw[0 * 128], w1 = pw[1 * 128], w2 = pw[2 * 128], w3 = pw[3 * 128];
        uint4 w4 = pw[4 * 128], w5 = pw[5 * 128], w6 = pw[6 * 128], w7 = pw[7 * 128];
        a0 = dot2(w0.x, av.x, a0); a0 = dot2(w0.y, av.y, a0); a0 = dot2(w0.z, av.z, a0); a0 = dot2(w0.w, av.w, a0);
        a1 = dot2(w1.x, av.x, a1); a1 = dot2(w1.y, av.y, a1); a1 = dot2(w1.z, av.z, a1); a1 = dot2(w1.w, av.w, a1);
        a2 = dot2(w2.x, av.x, a2); a2 = dot2(w2.y, av.y, a2); a2 = dot2(w2.z, av.z, a2); a2 = dot2(w2.w, av.w, a2);
        a3 = dot2(w3.x, av.x, a3); a3 = dot2(w3.y, av.y, a3); a3 = dot2(w3.z, av.z, a3); a3 = dot2(w3.w, av.w, a3);
        a4 = dot2(w4.x, av.x, a4); a4 = dot2(w4.y, av.y, a4); a4 = dot2(w4.z, av.z, a4); a4 = dot2(w4.w, av.w, a4);
        a5 = dot2(w5.x, av.x, a5); a5 = dot2(w5.y, av.y, a5); a5 = dot2(w5.z, av.z, a5); a5 = dot2(w5.w, av.w, a5);
        a6 = dot2(w6.x, av.x, a6); a6 = dot2(w6.y, av.y, a6); a6 = dot2(w6.z, av.z, a6); a6 = dot2(w6.w, av.w, a6);
        a7 = dot2(w7.x, av.x, a7); a7 = dot2(w7.y, av.y, a7); a7 = dot2(w7.z, av.z, a7); a7 = dot2(w7.w, av.w, a7);
      }
      float* pp = s_part + q2 * 1024 + og2;
      pp[0] = a0; pp[128] = a1; pp[256] = a2; pp[384] = a3;
      pp[512] = a4; pp[640] = a5; pp[768] = a6; pp[896] = a7;
    }
    __syncthreads();  // S2

    // ---- phase 3: combine gate partials (+embG, +bsum) + LSTM for pair (2i, 2i+1) ----
    if (tid < 128) {
      int i = tid;
      float gi0 = bsq0.x + eg0.x, gi1 = bsq0.y + eg0.y;
      float gf0 = bsq1.x + eg1.x, gf1 = bsq1.y + eg1.y;
      float gg0 = bsq2.x + eg2.x, gg1 = bsq2.y + eg2.y;
      float go0 = bsq3.x + eg3.x, go1 = bsq3.y + eg3.y;
      const float2* pp = (const float2*)s_part;
      #pragma unroll
      for (int q = 0; q < 8; ++q) {
        float2 v0 = pp[q * 512 + i];
        float2 v1 = pp[q * 512 + 128 + i];
        float2 v2 = pp[q * 512 + 256 + i];
        float2 v3 = pp[q * 512 + 384 + i];
        gi0 += v0.x; gi1 += v0.y; gf0 += v1.x; gf1 += v1.y;
        gg0 += v2.x; gg1 += v2.y; go0 += v3.x; go1 += v3.y;
      }
      float cn0 = sigf(gf0) * s_c[2 * i] + sigf(gi0) * tanhf(gg0);
      float cn1 = sigf(gf1) * s_c[2 * i + 1] + sigf(gi1) * tanhf(gg1);
      s_c[2 * i] = cn0; s_c[2 * i + 1] = cn1;
      float h0 = sigf(go0) * tanhf(cn0);
      float h1 = sigf(go1) * tanhf(cn1);
      s_actp[32 + i] = packh(h0, h1);
    }
    __syncthreads();  // S3

    // ---- phase 4: head-linear partials, dot2 from L2 stream (col c4, k-chunk q4) ----
    if (tid < 832) {
      float acc = 0.f;
      const uint4* ap = s_actp4 + 8 + q4 * 8;   // h pairs for k-chunk
      const uint4* wp = HWT + (q4 * 8) * HST + c4;
      #pragma unroll
      for (int j = 0; j < 8; ++j) {
        uint4 w = wp[j * HST];
        uint4 av = ap[j];
        acc = dot2(w.x, av.x, acc); acc = dot2(w.y, av.y, acc);
        acc = dot2(w.z, av.z, acc); acc = dot2(w.w, av.w, acc);
      }
      s_part[q4 * HST + c4] = acc;
    }
    __syncthreads();  // S4

    // ---- phase 5: combine + activations (wave-aligned) ----
    if (tid < 256) {
      float val = 0.f;
      if (tid < HST) {
        val = hbv;
        #pragma unroll
        for (int q = 0; q < 4; ++q) val += s_part[q * HST + tid];
      }
      int wv = tid >> 6;
      if (wv == 0) {            // key l2-normalize (fp32)
        float ss = val * val;
        for (int off = 32; off; off >>= 1) ss += __shfl_xor(ss, off);
        s_hd[tid] = val / fmaxf(sqrtf(ss), 1e-12f);
      } else if (wv == 1) {     // erase: sigmoid
        s_hd[tid] = sigf(val);
      } else if (wv == 2) {     // add: tanh
        s_hd[tid] = tanhf(val);
      } else {                  // wave 3: shift softmax + scalars
        int l = tid & 63;
        float a0 = __shfl(val, 0), a1 = __shfl(val, 1), a2 = __shfl(val, 2);
        float mx = fmaxf(a0, fmaxf(a1, a2));
        float e0 = expf(a0 - mx), e1 = expf(a1 - mx), e2 = expf(a2 - mx);
        float ss = e0 + e1 + e2;
        float r = 0.f;
        if (l == 0) r = e0 / ss;
        else if (l == 1) r = e1 / ss;
        else if (l == 2) r = e2 / ss;
        else if (l == 3) r = splus(val);          // beta  (col 195)
        else if (l == 4) r = sigf(val);           // gate  (col 196)
        else if (l == 5) r = 1.0f + splus(val);   // gamma (col 197)
        if (l < 16) s_hd[192 + l] = r;
      }
    }
    __syncthreads();  // S5

    // ---- phase 6: cosine sim (4 lanes per memory row) ----
    {
      const float* mrow = s_mem + n6 * MPAD + q6 * 16;
      const float* kp = s_hd + q6 * 16;
      float dot = 0.f, sq = 0.f;
      #pragma unroll
      for (int i = 0; i < 16; ++i) {
        float mv = mrow[i];
        dot = fmaf(mv, kp[i], dot);
        sq  = fmaf(mv, mv, sq);
      }
      dot += __shfl_xor(dot, 1); dot += __shfl_xor(dot, 2);
      sq  += __shfl_xor(sq, 1);  sq  += __shfl_xor(sq, 2);
      if (q6 == 0) s_sim[n6] = dot / fmaxf(sqrtf(sq), 1e-12f);
    }
    __syncthreads();  // S6

    // ---- phase 7: full addressing chain in one wave (4 slots/lane) ----
    if (tid < 64) {
      int l = tid;
      float beta = s_hd[195], gate = s_hd[196], gamma = s_hd[197];
      float sh0 = s_hd[192], sh1 = s_hd[193], sh2 = s_hd[194];
      float v0 = beta * s_sim[l], v1 = beta * s_sim[64 + l];
      float v2 = beta * s_sim[128 + l], v3 = beta * s_sim[192 + l];
      float mx = fmaxf(fmaxf(v0, v1), fmaxf(v2, v3));
      for (int off = 32; off; off >>= 1) mx = fmaxf(mx, __shfl_xor(mx, off));
      float e0 = expf(v0 - mx), e1 = expf(v1 - mx), e2 = expf(v2 - mx), e3 = expf(v3 - mx);
      float s = e0 + e1 + e2 + e3;
      for (int off = 32; off; off >>= 1) s += __shfl_xor(s, off);
      float inv = 1.0f / s, omg = 1.0f - gate;
      float wg[4];
      wg[0] = gate * e0 * inv + omg * s_rw[l];
      wg[1] = gate * e1 * inv + omg * s_rw[64 + l];
      wg[2] = gate * e2 * inv + omg * s_rw[128 + l];
      wg[3] = gate * e3 * inv + omg * s_rw[192 + l];
      float p[4]; float ps = 0.f;
      #pragma unroll
      for (int j = 0; j < 4; ++j) {
        float cu = (l == 0) ? wg[(j + 1) & 3] : wg[j];
        float up = __shfl(cu, (l + 1) & 63);
        float cd = (l == 63) ? wg[(j + 3) & 3] : wg[j];
        float dn = __shfl(cd, (l + 63) & 63);
        float wn = fmaf(sh0, up, fmaf(sh1, wg[j], sh2 * dn));
        p[j] = powf(wn, gamma);
        ps += p[j];
      }
      for (int off = 32; off; off >>= 1) ps += __shfl_xor(ps, off);
      float invp = 1.0f / ps;
      #pragma unroll
      for (int j = 0; j < 4; ++j) {
        float wv = p[j] * invp;
        s_w[l + 64 * j] = wv;
        s_rw[l + 64 * j] = wv;
      }
    }
    __syncthreads();  // S7

    // ---- phase 8: rv partials = w @ mem (16 n-chunks x 64 m) ----
    {
      float acc = 0.f;
      int n0 = q8 * 16;
      #pragma unroll
      for (int i = 0; i < 16; ++i) {
        int n = n0 + i;
        acc = fmaf(s_w[n], s_mem[n * MPAD + m8], acc);
      }
      s_part[q8 * 64 + m8] = acc;
    }
    __syncthreads();  // S8

    // ---- phase 9: rv combine (packed into s_actp[0:32)) + memory update ----
    if (tid < 32) {
      float a0 = 0.f, a1 = 0.f;
      #pragma unroll
      for (int q = 0; q < 16; ++q) {
        a0 += s_part[q * 64 + 2 * tid];
        a1 += s_part[q * 64 + 2 * tid + 1];
      }
      s_actp[tid] = packh(a0, a1);
    }
    for (int i = tid; i < NN * NM; i += 1024) {
      int n = i >> 6, m = i & 63;
      float wv = s_w[n];
      float cur = s_mem[n * MPAD + m];
      s_mem[n * MPAD + m] = cur * (1.f - wv * s_hd[64 + m]) + wv * s_hd[128 + m];
    }
    __syncthreads();  // S9

    if (!SPLIT) {
      // fused logits fallback: 4 outs x 40 k per thread (OUT2 [k][og], unpack act)
      {
        int ogo = tid & 127, qo = tid >> 7;
        const uint2* pw = OUT2 + (qo * 40) * 128 + ogo;
        float4 acc = {0.f, 0.f, 0.f, 0.f};
        #pragma unroll 8
        for (int kk = 0; kk < 40; ++kk) {
          int k = qo * 40 + kk;
          int hp = (k < NC) ? (32 + (k >> 1)) : ((k - NC) >> 1);
          unsigned u = s_actp[hp];
          float a = (k & 1) ? hhi(u) : hlo(u);
          uint2 w = pw[kk * 128];
          acc.x = fmaf(hlo(w.x), a, acc.x); acc.y = fmaf(hhi(w.x), a, acc.y);
          acc.z = fmaf(hlo(w.y), a, acc.z); acc.w = fmaf(hhi(w.y), a, acc.w);
        }
        ((float4*)s_part)[qo * 128 + ogo] = acc;
      }
      __syncthreads();
      if (tid < NV) {
        float r = out_b[tid];
        #pragma unroll
        for (int q = 0; q < 8; ++q) r += s_part[q * NV + tid];
        out[((size_t)(b * NS + t)) * NV + tid] = r;
      }
      __syncthreads();
    }
  }

  if (SPLIT && tid < 160) {
    unsigned v = (tid < 128) ? s_actp[32 + tid] : s_actp[tid - 128];
    hrv32[(size_t)(b * NS + NS - 1) * 160 + tid] = v;
  }
}

// ---------------- Logits GEMM: 8192 x 512, K=320 ([h, rv]), fp16 weights + packed acts ----------------
__launch_bounds__(512)
__global__ void ntm_logits(const char* __restrict__ ws, const float* __restrict__ out_b,
                           float* __restrict__ out)
{
  const uint2* OUT2 = (const uint2*)(ws + B_OUT2);
  const unsigned* hrv32 = (const unsigned*)(ws + B_HRV);
  __shared__ float s_z[16 * 321];
  const int tid = threadIdx.x;
  const int r0 = blockIdx.x * 16;
  {
    int r = tid >> 5, i0 = tid & 31;
    const unsigned* src = hrv32 + (size_t)(r0 + r) * 160;
    for (int i = i0; i < 160; i += 32) {
      unsigned u = src[i];
      s_z[r * 321 + 2 * i] = hlo(u);
      s_z[r * 321 + 2 * i + 1] = hhi(u);
    }
  }
  __syncthreads();
  const int og = tid & 127, rq = tid >> 7;
  const int rb = rq * 4;
  const uint2* pw = OUT2 + og;
  float4 a0 = {0,0,0,0}, a1 = a0, a2 = a0, a3 = a0;
  #pragma unroll 4
  for (int k = 0; k < KZ; ++k) {
    uint2 w = pw[k * 128];
    float w0 = hlo(w.x), w1 = hhi(w.x), w2 = hlo(w.y), w3 = hhi(w.y);
    float z0 = s_z[(rb + 0) * 321 + k], z1 = s_z[(rb + 1) * 321 + k];
    float z2 = s_z[(rb + 2) * 321 + k], z3 = s_z[(rb + 3) * 321 + k];
    a0.x = fmaf(w0, z0, a0.x); a0.y = fmaf(w1, z0, a0.y); a0.z = fmaf(w2, z0, a0.z); a0.w = fmaf(w3, z0, a0.w);
    a1.x = fmaf(w0, z1, a1.x); a1.y = fmaf(w1, z1, a1.y); a1.z = fmaf(w2, z1, a1.z); a1.w = fmaf(w3, z1, a1.w);
    a2.x = fmaf(w0, z2, a2.x); a2.y = fmaf(w1, z2, a2.y); a2.z = fmaf(w2, z2, a2.z); a2.w = fmaf(w3, z2, a2.w);
    a3.x = fmaf(w0, z3, a3.x); a3.y = fmaf(w1, z3, a3.y); a3.z = fmaf(w2, z3, a3.z); a3.w = fmaf(w3, z3, a3.w);
  }
  float4 ob = *(const float4*)(out_b + og * 4);
  a0.x += ob.x; a0.y += ob.y; a0.z += ob.z; a0.w += ob.w;
  a1.x += ob.x; a1.y += ob.y; a1.z += ob.z; a1.w += ob.w;
  a2.x += ob.x; a2.y += ob.y; a2.z += ob.z; a2.w += ob.w;
  a3.x += ob.x; a3.y += ob.y; a3.z += ob.z; a3.w += ob.w;
  float4* po = (float4*)(out + (size_t)(r0 + rb) * NV + og * 4);
  po[0 * (NV / 4)] = a0;
  po[1 * (NV / 4)] = a1;
  po[2 * (NV / 4)] = a2;
  po[3 * (NV / 4)] = a3;
}

extern "C" void kernel_launch(void* const* d_in, const int* in_sizes, int n_in,
                              void* d_out, int out_size, void* d_ws, size_t ws_size,
                              hipStream_t stream) {
  (void)in_sizes; (void)n_in; (void)out_size;
  const int*   x       = (const int*)  d_in[0];
  const float* emb     = (const float*)d_in[1];
  const float* W_ih    = (const float*)d_in[2];
  const float* W_hh    = (const float*)d_in[3];
  const float* b_ih    = (const float*)d_in[4];
  const float* b_hh    = (const float*)d_in[5];
  const float* key_W   = (const float*)d_in[6];
  const float* key_b   = (const float*)d_in[7];
  const float* beta_W  = (const float*)d_in[8];
  const float* beta_b  = (const float*)d_in[9];
  const float* gate_W  = (const float*)d_in[10];
  const float* gate_b  = (const float*)d_in[11];
  const float* shift_W = (const float*)d_in[12];
  const float* shift_b = (const float*)d_in[13];
  const float* gamma_W = (const float*)d_in[14];
  const float* gamma_b = (const float*)d_in[15];
  const float* erase_W = (const float*)d_in[16];
  const float* erase_b = (const float*)d_in[17];
  const float* add_W   = (const float*)d_in[18];
  const float* add_b   = (const float*)d_in[19];
  const float* out_W   = (const float*)d_in[20];
  const float* out_b   = (const float*)d_in[21];
  const float* mem_init= (const float*)d_in[22];
  char* ws   = (char*)d_ws;
  float* out = (float*)d_out;

  int prep_blocks = (PREP1_ITEMS + 255) / 256;
  ntm_prep<<<prep_blocks, 256, 0, stream>>>(W_ih, W_hh, b_ih, b_hh, key_W, key_b,
      beta_W, beta_b, gate_W, gate_b, shift_W, shift_b, gamma_W, gamma_b,
      erase_W, erase_b, add_W, add_b, out_W, ws);
  ntm_prep_embg<<<NV, 256, 0, stream>>>(emb, W_ih, ws);

  bool split = (ws_size >= (size_t)WS_SPLIT_BYTES);
  if (split) {
    hipFuncSetAttribute((const void*)ntm_main<1>, hipFuncAttributeMaxDynamicSharedMemorySize,
                        SMEM_BYTES);
    ntm_main<1><<<NB, 1024, SMEM_BYTES, stream>>>(x, out_b, mem_init, ws, out);
    ntm_logits<<<(NB * NS) / 16, 512, 0, stream>>>(ws, out_b, out);
  } else {
    hipFuncSetAttribute((const void*)ntm_main<0>, hipFuncAttributeMaxDynamicSharedMemorySize,
                        SMEM_BYTES);
    ntm_main<0><<<NB, 1024, SMEM_BYTES, stream>>>(x, out_b, mem_init, ws, out);
  }
}